// Round 6
// baseline (127.596 us; speedup 1.0000x reference)
//
#include <hip/hip_runtime.h>
#include <math.h>

#define NP 4
#define NN 8192
#define NM 8192

// ws layout (floats):
//   packed A (cad transformed, x,y,z,h=0.5|v|^2): float4[NP*NM] at 0
//   packed B (cam):                               float4[NP*NN] after A
//   minA: float[NP*NM] at MINS_OFF, minB: float[NP*NN] right after
#define PK_A_F4 0
#define PK_B_F4 (NP * NM)
#define MINS_OFF ((NP * NM + NP * NN) * 4)
#define MINB_REL (NP * NM)

#define TQ 8        // queries per thread
#define QT 2048     // queries per block (256 * TQ)
#define SPLITS 32   // target-dim splits -> 1024 blocks = 4 blocks/CU
#define SPAN 256    // targets per block (== NN/SPLITS)

#define RED_BLOCKS 128  // finalize reduction blocks

__device__ inline float min3f(float a, float b, float c) {
    float d;
    asm("v_min3_f32 %0, %1, %2, %3" : "=v"(d) : "v"(a), "v"(b), "v"(c));
    return d;
}

__device__ inline void make_transform(const float* __restrict__ quat,
                                      const float* __restrict__ tra,
                                      int p, float T[12]) {
    float q0 = quat[p * 4 + 0], q1 = quat[p * 4 + 1];
    float q2 = quat[p * 4 + 2], q3 = quat[p * 4 + 3];
    float inv = 1.0f / sqrtf(q0 * q0 + q1 * q1 + q2 * q2 + q3 * q3);
    float a = q0 * inv, b = q1 * inv, c = q2 * inv, d = q3 * inv;
    T[0] = 1.0f - 2.0f * c * c - 2.0f * d * d;
    T[1] = 2.0f * b * c - 2.0f * a * d;
    T[2] = 2.0f * a * c + 2.0f * b * d;
    T[3] = tra[p * 3 + 0];
    T[4] = 2.0f * b * c + 2.0f * a * d;
    T[5] = 1.0f - 2.0f * b * b - 2.0f * d * d;
    T[6] = 2.0f * c * d - 2.0f * a * b;
    T[7] = tra[p * 3 + 1];
    T[8] = 2.0f * b * d - 2.0f * a * c;
    T[9] = 2.0f * a * b + 2.0f * c * d;
    T[10] = 1.0f - 2.0f * b * b - 2.0f * c * c;
    T[11] = tra[p * 3 + 2];
}

// 256 blocks x 256 threads: transform+pack both clouds into float4 arrays,
// init min arrays to +inf, emit transforms to out[1..64], zero out[0].
__global__ __launch_bounds__(256) void prep_kernel(
    const float* __restrict__ cam, const float* __restrict__ cad,
    const float* __restrict__ quat, const float* __restrict__ tra,
    float* __restrict__ ws, float* __restrict__ out) {
    int idx = blockIdx.x * 256 + threadIdx.x;  // [0, NP*(NM+NN))
    const float INF = __uint_as_float(0x7f800000u);

    if (idx < NP * NM) {
        int p = idx >> 13;
        int m = idx & (NM - 1);
        float T[12];
        make_transform(quat, tra, p, T);
        float x = cad[(p * NM + m) * 3 + 0];
        float y = cad[(p * NM + m) * 3 + 1];
        float z = cad[(p * NM + m) * 3 + 2];
        float vx = fmaf(T[0], x, fmaf(T[1], y, fmaf(T[2], z, T[3])));
        float vy = fmaf(T[4], x, fmaf(T[5], y, fmaf(T[6], z, T[7])));
        float vz = fmaf(T[8], x, fmaf(T[9], y, fmaf(T[10], z, T[11])));
        float h = 0.5f * (vx * vx + vy * vy + vz * vz);
        ((float4*)ws)[PK_A_F4 + idx] = make_float4(vx, vy, vz, h);
        ws[MINS_OFF + idx] = INF;
    } else {
        int k = idx - NP * NM;
        float vx = cam[k * 3 + 0];
        float vy = cam[k * 3 + 1];
        float vz = cam[k * 3 + 2];
        float h = 0.5f * (vx * vx + vy * vy + vz * vz);
        ((float4*)ws)[PK_B_F4 + k] = make_float4(vx, vy, vz, h);
        ws[MINS_OFF + MINB_REL + k] = INF;
    }

    if (idx < 64) {
        int p2 = idx >> 4;
        int r = (idx >> 2) & 3;
        int c = idx & 3;
        float T[12];
        make_transform(quat, tra, p2, T);
        float v;
        if (r == 3)
            v = (c == 3) ? 1.0f : 0.0f;
        else
            v = T[r * 4 + c];
        out[1 + idx] = v;
    } else if (idx == 64) {
        out[0] = 0.0f;
    }
}

// grid (NM/QT, SPLITS, 2*NP) = 1024 blocks = 4 blocks/CU.
// Targets are wave-uniform -> read via uniform index from the packed global
// array (separate __restrict__ pointer from the min arrays so the compiler
// can prove no alias with the atomics and emit s_load): target coords live
// in SGPRs, no LDS at all, VALU is the only hot pipe (~3.6 inst/pair).
__global__ __launch_bounds__(256) void chamfer_kernel(
    const float4* __restrict__ packed, float* __restrict__ mins) {
    int tid = threadIdx.x;
    int p = blockIdx.z >> 1;
    int role = blockIdx.z & 1;

    const float4* Q;
    const float4* T;
    float* minarr;
    if (role == 0) {  // queries = transformed cad, targets = cam -> minA
        Q = packed + PK_A_F4 + p * NM;
        T = packed + PK_B_F4 + p * NN;
        minarr = mins + p * NM;
    } else {  // queries = cam, targets = transformed cad -> minB
        Q = packed + PK_B_F4 + p * NN;
        T = packed + PK_A_F4 + p * NM;
        minarr = mins + MINB_REL + p * NN;
    }

    const float INF = __uint_as_float(0x7f800000u);
    int q0 = blockIdx.x * QT + tid;
    float qx[TQ], qy[TQ], qz[TQ], qw[TQ], tmin[TQ];
#pragma unroll
    for (int k = 0; k < TQ; ++k) {
        float4 v = Q[q0 + k * 256];
        qx[k] = v.x; qy[k] = v.y; qz[k] = v.z; qw[k] = v.w;
        tmin[k] = INF;
    }

    int tbase = blockIdx.y * SPAN;
#pragma unroll 4
    for (int j = 0; j < SPAN; j += 2) {
        float4 t0 = T[tbase + j];
        float4 t1 = T[tbase + j + 1];
#pragma unroll
        for (int k = 0; k < TQ; ++k) {
            float s0 = fmaf(-qx[k], t0.x, fmaf(-qy[k], t0.y, fmaf(-qz[k], t0.z, t0.w)));
            float s1 = fmaf(-qx[k], t1.x, fmaf(-qy[k], t1.y, fmaf(-qz[k], t1.z, t1.w)));
            tmin[k] = min3f(tmin[k], s0, s1);
        }
    }

#pragma unroll
    for (int k = 0; k < TQ; ++k) {
        float d2 = 2.0f * (qw[k] + tmin[k]);
        d2 = fmaxf(d2, 0.0f);
        atomicMin((unsigned int*)&minarr[q0 + k * 256], __float_as_uint(d2));
    }
}

__global__ __launch_bounds__(256) void finalize_kernel(
    const float* __restrict__ ws, const float* __restrict__ w,
    float* __restrict__ out) {
    // minA (NP*NM) then minB (NP*NN), contiguous 65536 floats at MINS_OFF.
    // part index for element j: (j >> 13) & 3 (same layout in both halves).
    const float* vals = ws + MINS_OFF;
    int i = blockIdx.x * 256 + threadIdx.x;  // [0, 32768)
    int tid = threadIdx.x;

    float wl[4] = {w[0], w[1], w[2], w[3]};

    int i2 = i + 32768;
    float acc = wl[(i >> 13) & 3] * sqrtf(vals[i]) +
                wl[(i2 >> 13) & 3] * sqrtf(vals[i2]);

#pragma unroll
    for (int off = 32; off > 0; off >>= 1) acc += __shfl_down(acc, off, 64);

    __shared__ float wsum[4];
    if ((tid & 63) == 0) wsum[tid >> 6] = acc;
    __syncthreads();
    if (tid == 0) {
        float blocksum = (wsum[0] + wsum[1] + wsum[2] + wsum[3]) * (1.0f / 8192.0f);
        atomicAdd(out, blocksum);
    }
}

extern "C" void kernel_launch(void* const* d_in, const int* in_sizes, int n_in,
                              void* d_out, int out_size, void* d_ws, size_t ws_size,
                              hipStream_t stream) {
    const float* cam = (const float*)d_in[0];   // (P, N, 3)
    const float* cad = (const float*)d_in[1];   // (P, M, 3)
    const float* w = (const float*)d_in[2];     // (P,)
    const float* quat = (const float*)d_in[3];  // (P, 4)
    const float* tra = (const float*)d_in[4];   // (P, 3, 1)
    float* out = (float*)d_out;
    float* ws = (float*)d_ws;

    prep_kernel<<<(NP * (NM + NN)) / 256, 256, 0, stream>>>(cam, cad, quat, tra, ws, out);

    dim3 grid(NM / QT, SPLITS, 2 * NP);
    chamfer_kernel<<<grid, 256, 0, stream>>>((const float4*)ws, ws + MINS_OFF);

    finalize_kernel<<<RED_BLOCKS, 256, 0, stream>>>(ws, w, out);
}

// Round 7
// 109.275 us; speedup vs baseline: 1.1677x; 1.1677x over previous
//
#include <hip/hip_runtime.h>
#include <math.h>

#define NP 4
#define NN 8192
#define NM 8192

// ws layout (floats):
//   packed A (cad transformed, x,y,z,h=0.5|v|^2): float4[NP*NM] at 0
//   packed B (cam):                               float4[NP*NN] after A
//   minA: float[NP*NM] at MINS_OFF, minB: float[NP*NN] right after
#define PK_A_F4 0
#define PK_B_F4 (NP * NM)
#define MINS_OFF ((NP * NM + NP * NN) * 4)
#define MINB_REL (NP * NM)

#define TQ 16       // queries per thread (VALU:LDS issue ratio ~9:1)
#define QT 4096     // queries per block (256 * TQ)
#define SPLITS 64   // target-dim splits -> 1024 blocks, 3-4 resident/CU
#define SPAN 128    // targets per block (== NN/SPLITS)

#define RED_BLOCKS 128  // finalize reduction blocks

__device__ inline float min3f(float a, float b, float c) {
    float d;
    asm("v_min3_f32 %0, %1, %2, %3" : "=v"(d) : "v"(a), "v"(b), "v"(c));
    return d;
}

__device__ inline void make_transform(const float* __restrict__ quat,
                                      const float* __restrict__ tra,
                                      int p, float T[12]) {
    float q0 = quat[p * 4 + 0], q1 = quat[p * 4 + 1];
    float q2 = quat[p * 4 + 2], q3 = quat[p * 4 + 3];
    float inv = 1.0f / sqrtf(q0 * q0 + q1 * q1 + q2 * q2 + q3 * q3);
    float a = q0 * inv, b = q1 * inv, c = q2 * inv, d = q3 * inv;
    T[0] = 1.0f - 2.0f * c * c - 2.0f * d * d;
    T[1] = 2.0f * b * c - 2.0f * a * d;
    T[2] = 2.0f * a * c + 2.0f * b * d;
    T[3] = tra[p * 3 + 0];
    T[4] = 2.0f * b * c + 2.0f * a * d;
    T[5] = 1.0f - 2.0f * b * b - 2.0f * d * d;
    T[6] = 2.0f * c * d - 2.0f * a * b;
    T[7] = tra[p * 3 + 1];
    T[8] = 2.0f * b * d - 2.0f * a * c;
    T[9] = 2.0f * a * b + 2.0f * c * d;
    T[10] = 1.0f - 2.0f * b * b - 2.0f * c * c;
    T[11] = tra[p * 3 + 2];
}

// 256 blocks x 256 threads: transform+pack both clouds into float4 arrays,
// init min arrays to +inf, emit transforms to out[1..64], zero out[0].
__global__ __launch_bounds__(256) void prep_kernel(
    const float* __restrict__ cam, const float* __restrict__ cad,
    const float* __restrict__ quat, const float* __restrict__ tra,
    float* __restrict__ ws, float* __restrict__ out) {
    int idx = blockIdx.x * 256 + threadIdx.x;  // [0, NP*(NM+NN))
    const float INF = __uint_as_float(0x7f800000u);

    if (idx < NP * NM) {
        int p = idx >> 13;
        int m = idx & (NM - 1);
        float T[12];
        make_transform(quat, tra, p, T);
        float x = cad[(p * NM + m) * 3 + 0];
        float y = cad[(p * NM + m) * 3 + 1];
        float z = cad[(p * NM + m) * 3 + 2];
        float vx = fmaf(T[0], x, fmaf(T[1], y, fmaf(T[2], z, T[3])));
        float vy = fmaf(T[4], x, fmaf(T[5], y, fmaf(T[6], z, T[7])));
        float vz = fmaf(T[8], x, fmaf(T[9], y, fmaf(T[10], z, T[11])));
        float h = 0.5f * (vx * vx + vy * vy + vz * vz);
        ((float4*)ws)[PK_A_F4 + idx] = make_float4(vx, vy, vz, h);
        ws[MINS_OFF + idx] = INF;
    } else {
        int k = idx - NP * NM;
        float vx = cam[k * 3 + 0];
        float vy = cam[k * 3 + 1];
        float vz = cam[k * 3 + 2];
        float h = 0.5f * (vx * vx + vy * vy + vz * vz);
        ((float4*)ws)[PK_B_F4 + k] = make_float4(vx, vy, vz, h);
        ws[MINS_OFF + MINB_REL + k] = INF;
    }

    if (idx < 64) {
        int p2 = idx >> 4;
        int r = (idx >> 2) & 3;
        int c = idx & 3;
        float T[12];
        make_transform(quat, tra, p2, T);
        float v;
        if (r == 3)
            v = (c == 3) ? 1.0f : 0.0f;
        else
            v = T[r * 4 + c];
        out[1 + idx] = v;
    } else if (idx == 64) {
        out[0] = 0.0f;
    }
}

// grid (NM/QT, SPLITS, 2*NP) = 1024 blocks.
// LDS-staged broadcast targets (conflict-free); TQ=16 gives ~9 VALU inst per
// ds_read_b128 so the LDS pipe and its latency hide under arithmetic.
// __launch_bounds__(256,2): let the allocator keep 16 queries x 5 floats in
// architectural VGPRs (~110-130); 2-4 blocks resident per CU.
__global__ __launch_bounds__(256, 2) void chamfer_kernel(
    const float4* __restrict__ packed, float* __restrict__ mins) {
    int tid = threadIdx.x;
    int p = blockIdx.z >> 1;
    int role = blockIdx.z & 1;

    const float4* Q;
    const float4* T;
    float* minarr;
    if (role == 0) {  // queries = transformed cad, targets = cam -> minA
        Q = packed + PK_A_F4 + p * NM;
        T = packed + PK_B_F4 + p * NN;
        minarr = mins + p * NM;
    } else {  // queries = cam, targets = transformed cad -> minB
        Q = packed + PK_B_F4 + p * NN;
        T = packed + PK_A_F4 + p * NM;
        minarr = mins + MINB_REL + p * NN;
    }

    __shared__ float4 sT[SPAN];

    const float INF = __uint_as_float(0x7f800000u);
    int q0 = blockIdx.x * QT + tid;
    float qx[TQ], qy[TQ], qz[TQ], qw[TQ], tmin[TQ];
#pragma unroll
    for (int k = 0; k < TQ; ++k) {
        float4 v = Q[q0 + k * 256];
        qx[k] = v.x; qy[k] = v.y; qz[k] = v.z; qw[k] = v.w;
        tmin[k] = INF;
    }

    int tbase = blockIdx.y * SPAN;
    for (int j = tid; j < SPAN; j += 256) sT[j] = T[tbase + j];
    __syncthreads();

#pragma unroll 2
    for (int j = 0; j < SPAN; j += 2) {
        float4 t0 = sT[j];
        float4 t1 = sT[j + 1];
#pragma unroll
        for (int k = 0; k < TQ; ++k) {
            float s0 = fmaf(-qx[k], t0.x, fmaf(-qy[k], t0.y, fmaf(-qz[k], t0.z, t0.w)));
            float s1 = fmaf(-qx[k], t1.x, fmaf(-qy[k], t1.y, fmaf(-qz[k], t1.z, t1.w)));
            tmin[k] = min3f(tmin[k], s0, s1);
        }
    }

#pragma unroll
    for (int k = 0; k < TQ; ++k) {
        float d2 = 2.0f * (qw[k] + tmin[k]);
        d2 = fmaxf(d2, 0.0f);
        atomicMin((unsigned int*)&minarr[q0 + k * 256], __float_as_uint(d2));
    }
}

__global__ __launch_bounds__(256) void finalize_kernel(
    const float* __restrict__ ws, const float* __restrict__ w,
    float* __restrict__ out) {
    // minA (NP*NM) then minB (NP*NN), contiguous 65536 floats at MINS_OFF.
    // part index for element j: (j >> 13) & 3 (same layout in both halves).
    const float* vals = ws + MINS_OFF;
    int i = blockIdx.x * 256 + threadIdx.x;  // [0, 32768)
    int tid = threadIdx.x;

    float wl[4] = {w[0], w[1], w[2], w[3]};

    int i2 = i + 32768;
    float acc = wl[(i >> 13) & 3] * sqrtf(vals[i]) +
                wl[(i2 >> 13) & 3] * sqrtf(vals[i2]);

#pragma unroll
    for (int off = 32; off > 0; off >>= 1) acc += __shfl_down(acc, off, 64);

    __shared__ float wsum[4];
    if ((tid & 63) == 0) wsum[tid >> 6] = acc;
    __syncthreads();
    if (tid == 0) {
        float blocksum = (wsum[0] + wsum[1] + wsum[2] + wsum[3]) * (1.0f / 8192.0f);
        atomicAdd(out, blocksum);
    }
}

extern "C" void kernel_launch(void* const* d_in, const int* in_sizes, int n_in,
                              void* d_out, int out_size, void* d_ws, size_t ws_size,
                              hipStream_t stream) {
    const float* cam = (const float*)d_in[0];   // (P, N, 3)
    const float* cad = (const float*)d_in[1];   // (P, M, 3)
    const float* w = (const float*)d_in[2];     // (P,)
    const float* quat = (const float*)d_in[3];  // (P, 4)
    const float* tra = (const float*)d_in[4];   // (P, 3, 1)
    float* out = (float*)d_out;
    float* ws = (float*)d_ws;

    prep_kernel<<<(NP * (NM + NN)) / 256, 256, 0, stream>>>(cam, cad, quat, tra, ws, out);

    dim3 grid(NM / QT, SPLITS, 2 * NP);
    chamfer_kernel<<<grid, 256, 0, stream>>>((const float4*)ws, ws + MINS_OFF);

    finalize_kernel<<<RED_BLOCKS, 256, 0, stream>>>(ws, w, out);
}

// Round 8
// 105.436 us; speedup vs baseline: 1.2102x; 1.0364x over previous
//
#include <hip/hip_runtime.h>
#include <math.h>

#define NP 4
#define NN 8192
#define NM 8192

// ws layout (floats):
//   packed A (cad transformed, x,y,z,h=0.5|v|^2): float4[NP*NM] at 0
//   packed B (cam):                               float4[NP*NN] after A
//   minA: float[NP*NM] at MINS_OFF, minB: float[NP*NN] right after
#define PK_A_F4 0
#define PK_B_F4 (NP * NM)
#define MINS_OFF ((NP * NM + NP * NN) * 4)
#define MINB_REL (NP * NM)

#define TQ 8        // queries per thread
#define QT 2048     // queries per block (256 * TQ)
#define SPLITS 64   // target-dim splits -> grid (4,64,8) = 2048 blocks
#define SPAN 128    // targets per block (== NN/SPLITS)

#define RED_BLOCKS 128  // finalize reduction blocks

__device__ inline float min3f(float a, float b, float c) {
    float d;
    asm("v_min3_f32 %0, %1, %2, %3" : "=v"(d) : "v"(a), "v"(b), "v"(c));
    return d;
}

__device__ inline void make_transform(const float* __restrict__ quat,
                                      const float* __restrict__ tra,
                                      int p, float T[12]) {
    float q0 = quat[p * 4 + 0], q1 = quat[p * 4 + 1];
    float q2 = quat[p * 4 + 2], q3 = quat[p * 4 + 3];
    float inv = 1.0f / sqrtf(q0 * q0 + q1 * q1 + q2 * q2 + q3 * q3);
    float a = q0 * inv, b = q1 * inv, c = q2 * inv, d = q3 * inv;
    T[0] = 1.0f - 2.0f * c * c - 2.0f * d * d;
    T[1] = 2.0f * b * c - 2.0f * a * d;
    T[2] = 2.0f * a * c + 2.0f * b * d;
    T[3] = tra[p * 3 + 0];
    T[4] = 2.0f * b * c + 2.0f * a * d;
    T[5] = 1.0f - 2.0f * b * b - 2.0f * d * d;
    T[6] = 2.0f * c * d - 2.0f * a * b;
    T[7] = tra[p * 3 + 1];
    T[8] = 2.0f * b * d - 2.0f * a * c;
    T[9] = 2.0f * a * b + 2.0f * c * d;
    T[10] = 1.0f - 2.0f * b * b - 2.0f * c * c;
    T[11] = tra[p * 3 + 2];
}

// 96 blocks x 256 threads: transform+pack both clouds into float4 arrays,
// init min arrays to +inf, emit transforms to out[1..64], zero out[0].
__global__ __launch_bounds__(256) void prep_kernel(
    const float* __restrict__ cam, const float* __restrict__ cad,
    const float* __restrict__ quat, const float* __restrict__ tra,
    float* __restrict__ ws, float* __restrict__ out) {
    int idx = blockIdx.x * 256 + threadIdx.x;  // [0, NP*(NM+NN))
    const float INF = __uint_as_float(0x7f800000u);

    if (idx < NP * NM) {
        int p = idx >> 13;
        int m = idx & (NM - 1);
        float T[12];
        make_transform(quat, tra, p, T);
        float x = cad[(p * NM + m) * 3 + 0];
        float y = cad[(p * NM + m) * 3 + 1];
        float z = cad[(p * NM + m) * 3 + 2];
        float vx = fmaf(T[0], x, fmaf(T[1], y, fmaf(T[2], z, T[3])));
        float vy = fmaf(T[4], x, fmaf(T[5], y, fmaf(T[6], z, T[7])));
        float vz = fmaf(T[8], x, fmaf(T[9], y, fmaf(T[10], z, T[11])));
        float h = 0.5f * (vx * vx + vy * vy + vz * vz);
        ((float4*)ws)[PK_A_F4 + idx] = make_float4(vx, vy, vz, h);
        ws[MINS_OFF + idx] = INF;
    } else {
        int k = idx - NP * NM;
        float vx = cam[k * 3 + 0];
        float vy = cam[k * 3 + 1];
        float vz = cam[k * 3 + 2];
        float h = 0.5f * (vx * vx + vy * vy + vz * vz);
        ((float4*)ws)[PK_B_F4 + k] = make_float4(vx, vy, vz, h);
        ws[MINS_OFF + MINB_REL + k] = INF;
    }

    if (idx < 64) {
        int p2 = idx >> 4;
        int r = (idx >> 2) & 3;
        int c = idx & 3;
        float T[12];
        make_transform(quat, tra, p2, T);
        float v;
        if (r == 3)
            v = (c == 3) ? 1.0f : 0.0f;
        else
            v = T[r * 4 + c];
        out[1 + idx] = v;
    } else if (idx == 64) {
        out[0] = 0.0f;
    }
}

// grid (4, 64, 8) = 2048 blocks. Targets staged in LDS (broadcast reads,
// conflict-free). Software-pipelined: prefetch the next 4 targets into
// registers while 224 cycles of VALU run on the current 4 -> ds_read latency
// hidden even at 2 waves/SIMD. amdgpu_waves_per_eu(2,4) caps the allocator's
// occupancy target so the q arrays stay in architectural VGPRs (the default
// heuristic pinned VGPR_Count at ~56 and spilled to AGPRs = v_accvgpr VALU
// traffic, the persistent 2x over the 24us VALU floor).
__global__ __launch_bounds__(256)
__attribute__((amdgpu_waves_per_eu(2, 4)))
void chamfer_kernel(const float4* __restrict__ packed, float* __restrict__ mins) {
    int tid = threadIdx.x;
    int p = blockIdx.z >> 1;
    int role = blockIdx.z & 1;

    const float4* Q;
    const float4* T;
    float* minarr;
    if (role == 0) {  // queries = transformed cad, targets = cam -> minA
        Q = packed + PK_A_F4 + p * NM;
        T = packed + PK_B_F4 + p * NN;
        minarr = mins + p * NM;
    } else {  // queries = cam, targets = transformed cad -> minB
        Q = packed + PK_B_F4 + p * NN;
        T = packed + PK_A_F4 + p * NM;
        minarr = mins + MINB_REL + p * NN;
    }

    __shared__ float4 sT[SPAN];

    const float INF = __uint_as_float(0x7f800000u);
    int q0 = blockIdx.x * QT + tid;
    float qx[TQ], qy[TQ], qz[TQ], qw[TQ], tmin[TQ];
#pragma unroll
    for (int k = 0; k < TQ; ++k) {
        float4 v = Q[q0 + k * 256];
        qx[k] = v.x; qy[k] = v.y; qz[k] = v.z; qw[k] = v.w;
        tmin[k] = INF;
    }

    int tbase = blockIdx.y * SPAN;
    if (tid < SPAN) sT[tid] = T[tbase + tid];
    __syncthreads();

    float4 t0 = sT[0], t1 = sT[1], t2 = sT[2], t3 = sT[3];
#pragma unroll 2
    for (int j = 0; j < SPAN; j += 4) {
        int jn = (j + 4) & (SPAN - 1);  // last iter harmlessly reloads 0..3
        float4 n0 = sT[jn + 0];
        float4 n1 = sT[jn + 1];
        float4 n2 = sT[jn + 2];
        float4 n3 = sT[jn + 3];
#pragma unroll
        for (int k = 0; k < TQ; ++k) {
            float s0 = fmaf(-qx[k], t0.x, fmaf(-qy[k], t0.y, fmaf(-qz[k], t0.z, t0.w)));
            float s1 = fmaf(-qx[k], t1.x, fmaf(-qy[k], t1.y, fmaf(-qz[k], t1.z, t1.w)));
            float s2 = fmaf(-qx[k], t2.x, fmaf(-qy[k], t2.y, fmaf(-qz[k], t2.z, t2.w)));
            float s3 = fmaf(-qx[k], t3.x, fmaf(-qy[k], t3.y, fmaf(-qz[k], t3.z, t3.w)));
            tmin[k] = min3f(tmin[k], s0, s1);
            tmin[k] = min3f(tmin[k], s2, s3);
        }
        t0 = n0; t1 = n1; t2 = n2; t3 = n3;
    }

#pragma unroll
    for (int k = 0; k < TQ; ++k) {
        float d2 = 2.0f * (qw[k] + tmin[k]);
        d2 = fmaxf(d2, 0.0f);
        atomicMin((unsigned int*)&minarr[q0 + k * 256], __float_as_uint(d2));
    }
}

__global__ __launch_bounds__(256) void finalize_kernel(
    const float* __restrict__ ws, const float* __restrict__ w,
    float* __restrict__ out) {
    // minA (NP*NM) then minB (NP*NN), contiguous 65536 floats at MINS_OFF.
    // part index for element j: (j >> 13) & 3 (same layout in both halves).
    const float* vals = ws + MINS_OFF;
    int i = blockIdx.x * 256 + threadIdx.x;  // [0, 32768)
    int tid = threadIdx.x;

    float wl[4] = {w[0], w[1], w[2], w[3]};

    int i2 = i + 32768;
    float acc = wl[(i >> 13) & 3] * sqrtf(vals[i]) +
                wl[(i2 >> 13) & 3] * sqrtf(vals[i2]);

#pragma unroll
    for (int off = 32; off > 0; off >>= 1) acc += __shfl_down(acc, off, 64);

    __shared__ float wsum[4];
    if ((tid & 63) == 0) wsum[tid >> 6] = acc;
    __syncthreads();
    if (tid == 0) {
        float blocksum = (wsum[0] + wsum[1] + wsum[2] + wsum[3]) * (1.0f / 8192.0f);
        atomicAdd(out, blocksum);
    }
}

extern "C" void kernel_launch(void* const* d_in, const int* in_sizes, int n_in,
                              void* d_out, int out_size, void* d_ws, size_t ws_size,
                              hipStream_t stream) {
    const float* cam = (const float*)d_in[0];   // (P, N, 3)
    const float* cad = (const float*)d_in[1];   // (P, M, 3)
    const float* w = (const float*)d_in[2];     // (P,)
    const float* quat = (const float*)d_in[3];  // (P, 4)
    const float* tra = (const float*)d_in[4];   // (P, 3, 1)
    float* out = (float*)d_out;
    float* ws = (float*)d_ws;

    prep_kernel<<<(NP * (NM + NN)) / 256, 256, 0, stream>>>(cam, cad, quat, tra, ws, out);

    dim3 grid(NM / QT, SPLITS, 2 * NP);
    chamfer_kernel<<<grid, 256, 0, stream>>>((const float4*)ws, ws + MINS_OFF);

    finalize_kernel<<<RED_BLOCKS, 256, 0, stream>>>(ws, w, out);
}